// Round 7
// baseline (187.776 us; speedup 1.0000x reference)
//
#include <hip/hip_runtime.h>
#include <hip/hip_bf16.h>

typedef __bf16 bf16_t;
typedef bf16_t bf16x8 __attribute__((ext_vector_type(8)));
typedef bf16_t bf16x4 __attribute__((ext_vector_type(4)));
typedef float  f32x4  __attribute__((ext_vector_type(4)));
typedef float  f32x16 __attribute__((ext_vector_type(16)));

__device__ __forceinline__ f32x4 mfma16(bf16x8 a, bf16x8 b, f32x4 c) {
  return __builtin_amdgcn_mfma_f32_16x16x32_bf16(a, b, c, 0, 0, 0);
}
__device__ __forceinline__ f32x16 mfma32(bf16x8 a, bf16x8 b, f32x16 c) {
  return __builtin_amdgcn_mfma_f32_32x32x16_bf16(a, b, c, 0, 0, 0);
}

// ---------------- fused cast f32 -> bf16 for all 5 tensors ----------------
// regions in float4 units:
// features [0,1048576) | wq [..,1310720) | wk [..,1376256) | wv [..,1441792) | wo [..,1703936)
__global__ __launch_bounds__(256) void cast_all_k(const float* __restrict__ f,
                                                  const float* __restrict__ wq,
                                                  const float* __restrict__ wk,
                                                  const float* __restrict__ wv,
                                                  const float* __restrict__ wo,
                                                  bf16_t* __restrict__ Xbf,
                                                  bf16_t* __restrict__ Wqkv,
                                                  bf16_t* __restrict__ Wo) {
  int i = blockIdx.x * 256 + threadIdx.x;
  const float* src; bf16_t* dst; int off;
  if (i < 1048576)      { src = f;  dst = Xbf;                 off = 0; }
  else if (i < 1310720) { src = wq; dst = Wqkv;                off = 1048576; }
  else if (i < 1376256) { src = wk; dst = Wqkv + 1024 * 1024;  off = 1310720; }
  else if (i < 1441792) { src = wv; dst = Wqkv + 1280 * 1024;  off = 1376256; }
  else if (i < 1703936) { src = wo; dst = Wo;                  off = 1441792; }
  else return;
  int j = i - off;
  float4 v = reinterpret_cast<const float4*>(src)[j];
  bf16x4 o = { (bf16_t)v.x, (bf16_t)v.y, (bf16_t)v.z, (bf16_t)v.w };
  reinterpret_cast<bf16x4*>(dst)[j] = o;
}

// ---------------- GEMM: C[M,N] = A[M,K] * B[N,K]^T, bf16 in, f32 out ------------
// 128x128 tile, BK=64, 4 waves, double-buffered LDS, issue-early/drain-late.
__global__ __launch_bounds__(256) void gemm_bt(const bf16_t* __restrict__ A,
                                               const bf16_t* __restrict__ B,
                                               float* __restrict__ C,
                                               int M, int N, int K) {
  __shared__ __align__(16) unsigned short sA[2][128 * 64];
  __shared__ __align__(16) unsigned short sB[2][128 * 64];
  const int tid = threadIdx.x;
  const int lane = tid & 63;
  const int wid = tid >> 6;
  const int wm = wid >> 1, wn = wid & 1;
  const int lr = lane & 15, lg = lane >> 4;
  const int m0 = blockIdx.y * 128, n0 = blockIdx.x * 128;

  f32x4 acc[4][4] = {};

  auto STAGE = [&](int buf, int k0) {
#pragma unroll
    for (int r = 0; r < 4; ++r) {
      int e = r * 2048 + tid * 8;
      int row = e >> 6;
      int c = ((e >> 3) & 7) ^ (row & 7);
      const bf16_t* ga = A + (size_t)(m0 + row) * K + k0 + c * 8;
      __builtin_amdgcn_global_load_lds(
          (const __attribute__((address_space(1))) void*)ga,
          (__attribute__((address_space(3))) void*)(&sA[buf][r * 2048 + wid * 512]), 16, 0, 0);
      const bf16_t* gb = B + (size_t)(n0 + row) * K + k0 + c * 8;
      __builtin_amdgcn_global_load_lds(
          (const __attribute__((address_space(1))) void*)gb,
          (__attribute__((address_space(3))) void*)(&sB[buf][r * 2048 + wid * 512]), 16, 0, 0);
    }
  };

  const int nt = K >> 6;
  STAGE(0, 0);
  __syncthreads();
  int cur = 0;
  for (int t = 0; t < nt; ++t) {
    if (t + 1 < nt) STAGE(cur ^ 1, (t + 1) << 6);
#pragma unroll
    for (int ks = 0; ks < 2; ++ks) {
      bf16x8 afr[4], bfr[4];
#pragma unroll
      for (int m = 0; m < 4; ++m) {
        int row = wm * 64 + m * 16 + lr;
        int sc = (ks * 4 + lg) ^ (row & 7);
        afr[m] = *reinterpret_cast<const bf16x8*>(&sA[cur][row * 64 + sc * 8]);
      }
#pragma unroll
      for (int n = 0; n < 4; ++n) {
        int row = wn * 64 + n * 16 + lr;
        int sc = (ks * 4 + lg) ^ (row & 7);
        bfr[n] = *reinterpret_cast<const bf16x8*>(&sB[cur][row * 64 + sc * 8]);
      }
#pragma unroll
      for (int m = 0; m < 4; ++m)
#pragma unroll
        for (int n = 0; n < 4; ++n)
          acc[m][n] = mfma16(afr[m], bfr[n], acc[m][n]);
    }
    __syncthreads();
    cur ^= 1;
  }
#pragma unroll
  for (int m = 0; m < 4; ++m)
#pragma unroll
    for (int n = 0; n < 4; ++n) {
      int row = m0 + wm * 64 + m * 16 + lg * 4;
      int col = n0 + wn * 64 + n * 16 + lr;
#pragma unroll
      for (int r2 = 0; r2 < 4; ++r2)
        C[(size_t)(row + r2) * N + col] = acc[m][n][r2];
    }
}

// ---------------- RMSNorm of q (1024) and k (256) rows, emit bf16 ----------------
__global__ __launch_bounds__(256) void rmsnorm_k(const float* __restrict__ qkv,
                                                 const float* __restrict__ qw,
                                                 const float* __restrict__ kw,
                                                 bf16_t* __restrict__ qn,
                                                 bf16_t* __restrict__ kn) {
  const int row = blockIdx.x;
  const int b = row >> 11, s = row & 2047;
  const int tid = threadIdx.x;
  const float* rp = qkv + (size_t)row * 1536;
  float4 q4 = *reinterpret_cast<const float4*>(rp + tid * 4);
  float kv1 = rp[1024 + tid];
  float sq = q4.x * q4.x + q4.y * q4.y + q4.z * q4.z + q4.w * q4.w;
  float sk = kv1 * kv1;
#pragma unroll
  for (int d = 1; d < 64; d <<= 1) {
    sq += __shfl_xor(sq, d, 64);
    sk += __shfl_xor(sk, d, 64);
  }
  __shared__ float red[2][4];
  if ((tid & 63) == 0) { red[0][tid >> 6] = sq; red[1][tid >> 6] = sk; }
  __syncthreads();
  sq = red[0][0] + red[0][1] + red[0][2] + red[0][3];
  sk = red[1][0] + red[1][1] + red[1][2] + red[1][3];
  const float rq = rsqrtf(sq * (1.0f / 1024.0f) + 1e-6f);
  const float rk = rsqrtf(sk * (1.0f / 256.0f) + 1e-6f);
  float4 w4 = *reinterpret_cast<const float4*>(qw + tid * 4);
  const int c = tid * 4, hh = c >> 6, d0 = c & 63;
  bf16x4 o = { (bf16_t)(q4.x * rq * w4.x), (bf16_t)(q4.y * rq * w4.y),
               (bf16_t)(q4.z * rq * w4.z), (bf16_t)(q4.w * rq * w4.w) };
  *reinterpret_cast<bf16x4*>(qn + ((size_t)((b * 16 + hh) * 2048 + s)) * 64 + d0) = o;
  const int kvh = tid >> 6, dk = tid & 63;
  kn[((size_t)((b * 4 + kvh) * 2048 + s)) * 64 + dk] = (bf16_t)(kv1 * rk * kw[tid]);
}

// ---------------- V transpose: qkv -> vt[bkv][kt=S/32][d=64][kk=32] bf16 ---------
__global__ __launch_bounds__(256) void transpose_v_k(const float* __restrict__ qkv,
                                                     bf16_t* __restrict__ vt) {
  __shared__ float t[64][65];
  const int s0 = blockIdx.x * 64;
  const int bkv = blockIdx.y;
  const int b = bkv >> 2, kv = bkv & 3;
  const int tid = threadIdx.x;
  const int r = tid >> 2, cg = (tid & 3) * 16;
  const float* src = qkv + (size_t)(b * 2048 + s0 + r) * 1536 + 1280 + kv * 64 + cg;
#pragma unroll
  for (int j = 0; j < 4; ++j) {
    float4 v = *reinterpret_cast<const float4*>(src + j * 4);
    t[r][cg + j * 4 + 0] = v.x; t[r][cg + j * 4 + 1] = v.y;
    t[r][cg + j * 4 + 2] = v.z; t[r][cg + j * 4 + 3] = v.w;
  }
  __syncthreads();
  const int dl = tid >> 4;
  const int sl = (tid & 15) * 4;           // 0..60, 4-aligned
  const int kt = (s0 >> 5) + (sl >> 5);    // global 32-key tile
  const int kk = sl & 31;
#pragma unroll
  for (int p = 0; p < 4; ++p) {
    const int d = dl + p * 16;
    bf16x4 o = { (bf16_t)t[sl + 0][d], (bf16_t)t[sl + 1][d],
                 (bf16_t)t[sl + 2][d], (bf16_t)t[sl + 3][d] };
    *reinterpret_cast<bf16x4*>(vt + (size_t)bkv * 131072 + (size_t)kt * 2048 + d * 32 + kk) = o;
  }
}

// ---------------- Flash attention, swapped-QK 32x32, 2-wave k-split --------------
// Grid (bkv, qpair, hsub): blockIdx.x = (b,kv) pins same-K/V blocks to one XCD L2.
// No K prefetch (TLP at 4 waves/SIMD hides L2 latency); shfl_xor cross-half ops
// (proven semantics). Descending tiles + defer-max; scores recomputed in exp pass.
__global__ __launch_bounds__(256, 4) void attn_k(const bf16_t* __restrict__ qn,
                                                 const bf16_t* __restrict__ kn,
                                                 const bf16_t* __restrict__ vt,
                                                 bf16_t* __restrict__ ao) {
  constexpr int S = 2048, D = 64, H = 16, KV = 4, WIN = 512;
  const int bkv = blockIdx.x;                     // 0..7 -> XCD selector
  const int b = bkv >> 2, kv = bkv & 3;
  const int h = kv * 4 + blockIdx.z;
  const int wid = threadIdx.x >> 6;
  const int pair = wid >> 1;
  const int kh = wid & 1;
  const int qblk = blockIdx.y * 2 + pair;
  const int lane = threadIdx.x & 63;
  const int c = lane & 31;                        // q for P, d for O
  const int hi = lane >> 5;
  const int qbase = qblk * 32;
  const int q = qbase + c;

  __shared__ float mls[2][2][2][32];              // [pair][kh][m|l][q]
  __shared__ float accbuf[2][64][33];             // [pair][lane][r], +1 pad

  const bf16_t* qp = qn + ((size_t)(b * H + h) * S + q) * D + hi * 8;
  bf16x8 qf[4];
#pragma unroll
  for (int cd = 0; cd < 4; ++cd) qf[cd] = *reinterpret_cast<const bf16x8*>(qp + cd * 16);

  const bf16_t* kb = kn + (size_t)bkv * S * D;
  const bf16_t* vb = vt + (size_t)bkv * 131072;   // [kt][d][kk] tiles

  const float L2E = 1.4426950408889634f;
  const float c1 = L2E / 8.0f;                    // log2e / sqrt(D)
  const float c2 = exp2f(-0.5f * (float)h) * L2E; // slope_h * log2e

  f32x16 acc0 = {}, acc1 = {};
  float m_run = -3.0e38f, l_run = 0.0f;

  const int ktTop = qbase >> 5;
  const int kt0 = (qbase >= WIN) ? ((qbase - WIN) >> 5) : 0;
  const int ktstart = ktTop - kh;

  for (int kt = ktstart; kt >= kt0; kt -= 2) {
    const int k0 = kt << 5;
    // ---- K + V loads issued together (independent; L2-resident) ----
    const bf16_t* kp = kb + (((size_t)k0 + c) << 6) + hi * 8;
    bf16x8 kf0 = *reinterpret_cast<const bf16x8*>(kp);
    bf16x8 kf1 = *reinterpret_cast<const bf16x8*>(kp + 16);
    bf16x8 kf2 = *reinterpret_cast<const bf16x8*>(kp + 32);
    bf16x8 kf3 = *reinterpret_cast<const bf16x8*>(kp + 48);
    const bf16_t* vp = vb + ((size_t)kt << 11) + c * 32 + hi * 8;
    bf16x8 v00 = *reinterpret_cast<const bf16x8*>(vp);
    bf16x8 v01 = *reinterpret_cast<const bf16x8*>(vp + 16);
    bf16x8 v10 = *reinterpret_cast<const bf16x8*>(vp + 1024);
    bf16x8 v11 = *reinterpret_cast<const bf16x8*>(vp + 1024 + 16);

    // ---- QK^T (swapped): A=K rows, B=Q rows ----
    f32x16 sfa = {};
    sfa = mfma32(kf0, qf[0], sfa);
    sfa = mfma32(kf1, qf[1], sfa);
    sfa = mfma32(kf2, qf[2], sfa);
    sfa = mfma32(kf3, qf[3], sfa);

    // ---- row max (scores recomputed in exp pass; keeps regs low) ----
    const bool edge = (kt == ktTop) | (k0 + WIN < qbase + 32);
    float pmax = -3.0e38f;
    const float bb = c2 * (float)(k0 + 4 * hi - q);
    if (edge) {
#pragma unroll
      for (int r = 0; r < 16; ++r) {
        const int rel = k0 + (r & 3) + 8 * (r >> 2) + 4 * hi - q;
        float tv = sfa[r] * c1 + c2 * (float)rel;
        tv = (rel > 0 || rel < -WIN) ? -3.0e38f : tv;
        pmax = fmaxf(pmax, tv);
      }
    } else {
#pragma unroll
      for (int r = 0; r < 16; ++r)
        pmax = fmaxf(pmax, fmaf(sfa[r], c1, fmaf((float)((r & 3) + 8 * (r >> 2)), c2, bb)));
    }
    pmax = fmaxf(pmax, __shfl_xor(pmax, 32, 64));
    // ---- defer-max rescale (rare) ----
    if (!__all(pmax <= m_run + 8.0f)) {
      const float mnew = fmaxf(m_run, pmax);
      const float sc = exp2f(m_run - mnew);
      m_run = mnew;
      l_run *= sc;
#pragma unroll
      for (int r = 0; r < 16; ++r) {
        const int qi = (r & 3) + 8 * (r >> 2) + 4 * hi;
        const float scr = __shfl(sc, qi, 64);
        acc0[r] *= scr;
        acc1[r] *= scr;
      }
    }
    // ---- P = exp2(score - m), pack bf16 ----
    float rs = 0.0f;
    unsigned w[8];
    if (edge) {
#pragma unroll
      for (int i = 0; i < 8; ++i) {
        float e2[2];
#pragma unroll
        for (int j = 0; j < 2; ++j) {
          const int r = 2 * i + j;
          const int rel = k0 + (r & 3) + 8 * (r >> 2) + 4 * hi - q;
          float tv = sfa[r] * c1 + c2 * (float)rel;
          tv = (rel > 0 || rel < -WIN) ? -3.0e38f : tv;
          e2[j] = exp2f(tv - m_run);
        }
        rs += e2[0] + e2[1];
        union { bf16_t hh[2]; unsigned u; } pk;
        pk.hh[0] = (bf16_t)e2[0]; pk.hh[1] = (bf16_t)e2[1];
        w[i] = pk.u;
      }
    } else {
#pragma unroll
      for (int i = 0; i < 8; ++i) {
        float e2[2];
#pragma unroll
        for (int j = 0; j < 2; ++j) {
          const int r = 2 * i + j;
          float tv = fmaf(sfa[r], c1, fmaf((float)((r & 3) + 8 * (r >> 2)), c2, bb));
          e2[j] = exp2f(tv - m_run);
        }
        rs += e2[0] + e2[1];
        union { bf16_t hh[2]; unsigned u; } pk;
        pk.hh[0] = (bf16_t)e2[0]; pk.hh[1] = (bf16_t)e2[1];
        w[i] = pk.u;
      }
    }
    rs += __shfl_xor(rs, 32, 64);
    l_run += rs;
    // ---- assemble P A-fragments via cross-hi word swaps (proven mapping) ----
    unsigned s0 = __shfl_xor(w[0], 32, 64), s1 = __shfl_xor(w[1], 32, 64);
    unsigned s2 = __shfl_xor(w[2], 32, 64), s3 = __shfl_xor(w[3], 32, 64);
    unsigned s4 = __shfl_xor(w[4], 32, 64), s5 = __shfl_xor(w[5], 32, 64);
    unsigned s6 = __shfl_xor(w[6], 32, 64), s7 = __shfl_xor(w[7], 32, 64);
    union { unsigned u[4]; bf16x8 v; } pa0, pa1;
    if (hi == 0) {
      pa0.u[0] = w[0]; pa0.u[1] = w[1]; pa0.u[2] = s0; pa0.u[3] = s1;
      pa1.u[0] = w[4]; pa1.u[1] = w[5]; pa1.u[2] = s4; pa1.u[3] = s5;
    } else {
      pa0.u[0] = s2; pa0.u[1] = s3; pa0.u[2] = w[2]; pa0.u[3] = w[3];
      pa1.u[0] = s6; pa1.u[1] = s7; pa1.u[2] = w[6]; pa1.u[3] = w[7];
    }
    // ---- PV ----
    acc0 = mfma32(pa0.v, v00, acc0);
    acc0 = mfma32(pa1.v, v01, acc0);
    acc1 = mfma32(pa0.v, v10, acc1);
    acc1 = mfma32(pa1.v, v11, acc1);
  }

  // ---- merge the two k-half partials ----
  mls[pair][kh][0][c] = m_run;
  mls[pair][kh][1][c] = l_run;
  __syncthreads();
  const float mo = mls[pair][kh ^ 1][0][c];
  const float lo = mls[pair][kh ^ 1][1][c];
  const float mt = fmaxf(m_run, mo);
  const float sc_self = exp2f(m_run - mt);
#pragma unroll
  for (int r = 0; r < 16; ++r) {
    const int qi = (r & 3) + 8 * (r >> 2) + 4 * hi;
    const float scr = __shfl(sc_self, qi, 64);
    acc0[r] *= scr;
    acc1[r] *= scr;
  }
  if (kh == 1) {
#pragma unroll
    for (int r = 0; r < 16; ++r) {
      accbuf[pair][lane][r] = acc0[r];
      accbuf[pair][lane][r + 16] = acc1[r];
    }
  }
  __syncthreads();
  if (kh == 0) {
    const float l_tot = l_run * sc_self + lo * exp2f(mo - mt);
#pragma unroll
    for (int r = 0; r < 16; ++r) {
      acc0[r] += accbuf[pair][lane][r];
      acc1[r] += accbuf[pair][lane][r + 16];
    }
#pragma unroll
    for (int r = 0; r < 16; ++r) {
      const int qi = (r & 3) + 8 * (r >> 2) + 4 * hi;
      const float lr = __shfl(l_tot, qi, 64);
      const float inv = 1.0f / lr;
      bf16_t* op = ao + ((size_t)(b * S + qbase + qi)) * 1024 + h * 64 + c;
      op[0]  = (bf16_t)(acc0[r] * inv);
      op[32] = (bf16_t)(acc1[r] * inv);
    }
  }
}

extern "C" void kernel_launch(void* const* d_in, const int* in_sizes, int n_in,
                              void* d_out, int out_size, void* d_ws, size_t ws_size,
                              hipStream_t stream) {
  const float* features = (const float*)d_in[0];
  const float* wq = (const float*)d_in[1];
  const float* wk = (const float*)d_in[2];
  const float* wv = (const float*)d_in[3];
  const float* wo = (const float*)d_in[4];
  const float* qw = (const float*)d_in[5];
  const float* kw = (const float*)d_in[6];
  float* out = (float*)d_out;

  bf16_t* Xbf  = (bf16_t*)d_ws;
  bf16_t* Wqkv = Xbf + 4096 * 1024;
  bf16_t* Wo   = Wqkv + 1536 * 1024;
  float*  QKVr = (float*)(Wo + 1024 * 1024);
  bf16_t* Qn   = (bf16_t*)(QKVr + 4096 * 1536);
  bf16_t* Kn   = Qn + 2 * 16 * 2048 * 64;
  bf16_t* Vt   = Kn + 2 * 4 * 2048 * 64;
  bf16_t* Ao   = Vt + 2 * 4 * 64 * 2048;

  cast_all_k<<<6656, 256, 0, stream>>>(features, wq, wk, wv, wo, Xbf, Wqkv, Wo);
  gemm_bt<<<dim3(12, 32), 256, 0, stream>>>(Xbf, Wqkv, QKVr, 4096, 1536, 1024);
  rmsnorm_k<<<4096, 256, 0, stream>>>(QKVr, qw, kw, Qn, Kn);
  transpose_v_k<<<dim3(32, 8), 256, 0, stream>>>(QKVr, Vt);
  attn_k<<<dim3(8, 32, 4), 256, 0, stream>>>(Qn, Kn, Vt, Ao);
  gemm_bt<<<dim3(8, 32), 256, 0, stream>>>(Ao, Wo, out, 4096, 1024, 1024);
}

// Round 8
// 97.691 us; speedup vs baseline: 1.9221x; 1.9221x over previous
//
#include <hip/hip_runtime.h>
#include <hip/hip_bf16.h>

typedef __bf16 bf16_t;
typedef bf16_t bf16x8 __attribute__((ext_vector_type(8)));
typedef bf16_t bf16x4 __attribute__((ext_vector_type(4)));
typedef float  f32x4  __attribute__((ext_vector_type(4)));
typedef float  f32x16 __attribute__((ext_vector_type(16)));

__device__ __forceinline__ f32x4 mfma16(bf16x8 a, bf16x8 b, f32x4 c) {
  return __builtin_amdgcn_mfma_f32_16x16x32_bf16(a, b, c, 0, 0, 0);
}
__device__ __forceinline__ f32x16 mfma32(bf16x8 a, bf16x8 b, f32x16 c) {
  return __builtin_amdgcn_mfma_f32_32x32x16_bf16(a, b, c, 0, 0, 0);
}

// ---------------- fused cast f32 -> bf16 for all 5 tensors ----------------
// regions in float4 units:
// features [0,1048576) | wq [..,1310720) | wk [..,1376256) | wv [..,1441792) | wo [..,1703936)
__global__ __launch_bounds__(256) void cast_all_k(const float* __restrict__ f,
                                                  const float* __restrict__ wq,
                                                  const float* __restrict__ wk,
                                                  const float* __restrict__ wv,
                                                  const float* __restrict__ wo,
                                                  bf16_t* __restrict__ Xbf,
                                                  bf16_t* __restrict__ Wqkv,
                                                  bf16_t* __restrict__ Wo) {
  int i = blockIdx.x * 256 + threadIdx.x;
  const float* src; bf16_t* dst; int off;
  if (i < 1048576)      { src = f;  dst = Xbf;                 off = 0; }
  else if (i < 1310720) { src = wq; dst = Wqkv;                off = 1048576; }
  else if (i < 1376256) { src = wk; dst = Wqkv + 1024 * 1024;  off = 1310720; }
  else if (i < 1441792) { src = wv; dst = Wqkv + 1280 * 1024;  off = 1376256; }
  else if (i < 1703936) { src = wo; dst = Wo;                  off = 1441792; }
  else return;
  int j = i - off;
  float4 v = reinterpret_cast<const float4*>(src)[j];
  bf16x4 o = { (bf16_t)v.x, (bf16_t)v.y, (bf16_t)v.z, (bf16_t)v.w };
  reinterpret_cast<bf16x4*>(dst)[j] = o;
}

// ---------------- GEMM: C[M,N] = A[M,K] * B[N,K]^T, bf16 in, f32 out ------------
// 128x128 tile, BK=64, 4 waves, double-buffered LDS, issue-early/drain-late.
__global__ __launch_bounds__(256) void gemm_bt(const bf16_t* __restrict__ A,
                                               const bf16_t* __restrict__ B,
                                               float* __restrict__ C,
                                               int M, int N, int K) {
  __shared__ __align__(16) unsigned short sA[2][128 * 64];
  __shared__ __align__(16) unsigned short sB[2][128 * 64];
  const int tid = threadIdx.x;
  const int lane = tid & 63;
  const int wid = tid >> 6;
  const int wm = wid >> 1, wn = wid & 1;
  const int lr = lane & 15, lg = lane >> 4;
  const int m0 = blockIdx.y * 128, n0 = blockIdx.x * 128;

  f32x4 acc[4][4] = {};

  auto STAGE = [&](int buf, int k0) {
#pragma unroll
    for (int r = 0; r < 4; ++r) {
      int e = r * 2048 + tid * 8;
      int row = e >> 6;
      int c = ((e >> 3) & 7) ^ (row & 7);
      const bf16_t* ga = A + (size_t)(m0 + row) * K + k0 + c * 8;
      __builtin_amdgcn_global_load_lds(
          (const __attribute__((address_space(1))) void*)ga,
          (__attribute__((address_space(3))) void*)(&sA[buf][r * 2048 + wid * 512]), 16, 0, 0);
      const bf16_t* gb = B + (size_t)(n0 + row) * K + k0 + c * 8;
      __builtin_amdgcn_global_load_lds(
          (const __attribute__((address_space(1))) void*)gb,
          (__attribute__((address_space(3))) void*)(&sB[buf][r * 2048 + wid * 512]), 16, 0, 0);
    }
  };

  const int nt = K >> 6;
  STAGE(0, 0);
  __syncthreads();
  int cur = 0;
  for (int t = 0; t < nt; ++t) {
    if (t + 1 < nt) STAGE(cur ^ 1, (t + 1) << 6);
#pragma unroll
    for (int ks = 0; ks < 2; ++ks) {
      bf16x8 afr[4], bfr[4];
#pragma unroll
      for (int m = 0; m < 4; ++m) {
        int row = wm * 64 + m * 16 + lr;
        int sc = (ks * 4 + lg) ^ (row & 7);
        afr[m] = *reinterpret_cast<const bf16x8*>(&sA[cur][row * 64 + sc * 8]);
      }
#pragma unroll
      for (int n = 0; n < 4; ++n) {
        int row = wn * 64 + n * 16 + lr;
        int sc = (ks * 4 + lg) ^ (row & 7);
        bfr[n] = *reinterpret_cast<const bf16x8*>(&sB[cur][row * 64 + sc * 8]);
      }
#pragma unroll
      for (int m = 0; m < 4; ++m)
#pragma unroll
        for (int n = 0; n < 4; ++n)
          acc[m][n] = mfma16(afr[m], bfr[n], acc[m][n]);
    }
    __syncthreads();
    cur ^= 1;
  }
#pragma unroll
  for (int m = 0; m < 4; ++m)
#pragma unroll
    for (int n = 0; n < 4; ++n) {
      int row = m0 + wm * 64 + m * 16 + lg * 4;
      int col = n0 + wn * 64 + n * 16 + lr;
#pragma unroll
      for (int r2 = 0; r2 < 4; ++r2)
        C[(size_t)(row + r2) * N + col] = acc[m][n][r2];
    }
}

// ---------------- RMSNorm of q (1024) and k (256) rows, emit bf16 ----------------
__global__ __launch_bounds__(256) void rmsnorm_k(const float* __restrict__ qkv,
                                                 const float* __restrict__ qw,
                                                 const float* __restrict__ kw,
                                                 bf16_t* __restrict__ qn,
                                                 bf16_t* __restrict__ kn) {
  const int row = blockIdx.x;
  const int b = row >> 11, s = row & 2047;
  const int tid = threadIdx.x;
  const float* rp = qkv + (size_t)row * 1536;
  float4 q4 = *reinterpret_cast<const float4*>(rp + tid * 4);
  float kv1 = rp[1024 + tid];
  float sq = q4.x * q4.x + q4.y * q4.y + q4.z * q4.z + q4.w * q4.w;
  float sk = kv1 * kv1;
#pragma unroll
  for (int d = 1; d < 64; d <<= 1) {
    sq += __shfl_xor(sq, d, 64);
    sk += __shfl_xor(sk, d, 64);
  }
  __shared__ float red[2][4];
  if ((tid & 63) == 0) { red[0][tid >> 6] = sq; red[1][tid >> 6] = sk; }
  __syncthreads();
  sq = red[0][0] + red[0][1] + red[0][2] + red[0][3];
  sk = red[1][0] + red[1][1] + red[1][2] + red[1][3];
  const float rq = rsqrtf(sq * (1.0f / 1024.0f) + 1e-6f);
  const float rk = rsqrtf(sk * (1.0f / 256.0f) + 1e-6f);
  float4 w4 = *reinterpret_cast<const float4*>(qw + tid * 4);
  const int c = tid * 4, hh = c >> 6, d0 = c & 63;
  bf16x4 o = { (bf16_t)(q4.x * rq * w4.x), (bf16_t)(q4.y * rq * w4.y),
               (bf16_t)(q4.z * rq * w4.z), (bf16_t)(q4.w * rq * w4.w) };
  *reinterpret_cast<bf16x4*>(qn + ((size_t)((b * 16 + hh) * 2048 + s)) * 64 + d0) = o;
  const int kvh = tid >> 6, dk = tid & 63;
  kn[((size_t)((b * 4 + kvh) * 2048 + s)) * 64 + dk] = (bf16_t)(kv1 * rk * kw[tid]);
}

// ---------------- V transpose: qkv -> vt[bkv][kt=S/32][d=64][kk=32] bf16 ---------
__global__ __launch_bounds__(256) void transpose_v_k(const float* __restrict__ qkv,
                                                     bf16_t* __restrict__ vt) {
  __shared__ float t[64][65];
  const int s0 = blockIdx.x * 64;
  const int bkv = blockIdx.y;
  const int b = bkv >> 2, kv = bkv & 3;
  const int tid = threadIdx.x;
  const int r = tid >> 2, cg = (tid & 3) * 16;
  const float* src = qkv + (size_t)(b * 2048 + s0 + r) * 1536 + 1280 + kv * 64 + cg;
#pragma unroll
  for (int j = 0; j < 4; ++j) {
    float4 v = *reinterpret_cast<const float4*>(src + j * 4);
    t[r][cg + j * 4 + 0] = v.x; t[r][cg + j * 4 + 1] = v.y;
    t[r][cg + j * 4 + 2] = v.z; t[r][cg + j * 4 + 3] = v.w;
  }
  __syncthreads();
  const int dl = tid >> 4;
  const int sl = (tid & 15) * 4;           // 0..60, 4-aligned
  const int kt = (s0 >> 5) + (sl >> 5);    // global 32-key tile
  const int kk = sl & 31;
#pragma unroll
  for (int p = 0; p < 4; ++p) {
    const int d = dl + p * 16;
    bf16x4 o = { (bf16_t)t[sl + 0][d], (bf16_t)t[sl + 1][d],
                 (bf16_t)t[sl + 2][d], (bf16_t)t[sl + 3][d] };
    *reinterpret_cast<bf16x4*>(vt + (size_t)bkv * 131072 + (size_t)kt * 2048 + d * 32 + kk) = o;
  }
}

// ---------------- Flash attention, swapped-QK 32x32, 2-wave k-split --------------
// R4-proven body (V loaded late, t[16] kept, shfl_xor exchanges, no prefetch;
// fits 64 arch-VGPRs without spill) + R5-proven locality: XCD-pinned bkv grid
// and coalesced vt[kt][d][kk] tiles.
__global__ __launch_bounds__(256, 4) void attn_k(const bf16_t* __restrict__ qn,
                                                 const bf16_t* __restrict__ kn,
                                                 const bf16_t* __restrict__ vt,
                                                 bf16_t* __restrict__ ao) {
  constexpr int S = 2048, D = 64, H = 16, KV = 4, WIN = 512;
  const int bkv = blockIdx.x;                     // 0..7 -> XCD selector
  const int b = bkv >> 2, kv = bkv & 3;
  const int h = kv * 4 + blockIdx.z;
  const int wid = threadIdx.x >> 6;
  const int pair = wid >> 1;
  const int kh = wid & 1;
  const int qblk = blockIdx.y * 2 + pair;
  const int lane = threadIdx.x & 63;
  const int c = lane & 31;                        // q for P, d for O
  const int hi = lane >> 5;
  const int qbase = qblk * 32;
  const int q = qbase + c;

  __shared__ float mls[2][2][2][32];              // [pair][kh][m|l][q]
  __shared__ float accbuf[2][64][33];             // [pair][lane][r], +1 pad

  const bf16_t* qp = qn + ((size_t)(b * H + h) * S + q) * D + hi * 8;
  bf16x8 qf[4];
#pragma unroll
  for (int cd = 0; cd < 4; ++cd) qf[cd] = *reinterpret_cast<const bf16x8*>(qp + cd * 16);

  const bf16_t* kb = kn + (size_t)bkv * S * D;
  const bf16_t* vb = vt + (size_t)bkv * 131072;   // [kt][d][kk] tiles

  const float L2E = 1.4426950408889634f;
  const float c1 = L2E / 8.0f;                    // log2e / sqrt(D)
  const float c2 = exp2f(-0.5f * (float)h) * L2E; // slope_h * log2e

  f32x16 acc0 = {}, acc1 = {};
  float m_run = -3.0e38f, l_run = 0.0f;

  const int ktTop = qbase >> 5;
  const int kt0 = (qbase >= WIN) ? ((qbase - WIN) >> 5) : 0;

  for (int kt = ktTop - kh; kt >= kt0; kt -= 2) {
    const int k0 = kt << 5;
    // ---- QK^T (swapped): A=K rows, B=Q rows; K loaded here (late, R4-style) ----
    const bf16_t* kp = kb + (((size_t)k0 + c) << 6) + hi * 8;
    f32x16 sfa = {};
#pragma unroll
    for (int cd = 0; cd < 4; ++cd) {
      bf16x8 kf = *reinterpret_cast<const bf16x8*>(kp + cd * 16);
      sfa = mfma32(kf, qf[cd], sfa);
    }
    // ---- bias + (edge) mask + row max ----
    const bool mtop = (kt == ktTop);
    const bool mbot = (k0 + WIN < qbase + 32);
    float t[16];
    float pmax = -3.0e38f;
    if (mtop | mbot) {
#pragma unroll
      for (int r = 0; r < 16; ++r) {
        const int kk = k0 + (r & 3) + 8 * (r >> 2) + 4 * hi;
        const int rel = kk - q;
        float tv = sfa[r] * c1 + c2 * (float)rel;
        if (rel > 0 || rel < -WIN) tv = -3.0e38f;
        t[r] = tv;
        pmax = fmaxf(pmax, tv);
      }
    } else {
      const float bb = c2 * (float)(k0 + 4 * hi - q);
#pragma unroll
      for (int r = 0; r < 16; ++r) {
        const float koff = (float)((r & 3) + 8 * (r >> 2));
        float tv = fmaf(sfa[r], c1, fmaf(koff, c2, bb));
        t[r] = tv;
        pmax = fmaxf(pmax, tv);
      }
    }
    pmax = fmaxf(pmax, __shfl_xor(pmax, 32, 64));
    // ---- defer-max rescale ----
    if (!__all(pmax <= m_run + 8.0f)) {
      const float mnew = fmaxf(m_run, pmax);
      const float sc = exp2f(m_run - mnew);
      m_run = mnew;
      l_run *= sc;
#pragma unroll
      for (int r = 0; r < 16; ++r) {
        const int qi = (r & 3) + 8 * (r >> 2) + 4 * hi;
        const float scr = __shfl(sc, qi, 64);
        acc0[r] *= scr;
        acc1[r] *= scr;
      }
    }
    // ---- P = exp2(t - m), packed bf16 ----
    float rs = 0.0f;
    unsigned w[8];
#pragma unroll
    for (int i = 0; i < 8; ++i) {
      float e0 = exp2f(t[2 * i] - m_run);
      float e1 = exp2f(t[2 * i + 1] - m_run);
      rs += e0 + e1;
      union { bf16_t hh[2]; unsigned u; } pk;
      pk.hh[0] = (bf16_t)e0; pk.hh[1] = (bf16_t)e1;
      w[i] = pk.u;
    }
    rs += __shfl_xor(rs, 32, 64);
    l_run += rs;
    // ---- assemble P A-fragments via cross-hi word swaps ----
    unsigned s0 = __shfl_xor(w[0], 32, 64), s1 = __shfl_xor(w[1], 32, 64);
    unsigned s2 = __shfl_xor(w[2], 32, 64), s3 = __shfl_xor(w[3], 32, 64);
    unsigned s4 = __shfl_xor(w[4], 32, 64), s5 = __shfl_xor(w[5], 32, 64);
    unsigned s6 = __shfl_xor(w[6], 32, 64), s7 = __shfl_xor(w[7], 32, 64);
    union { unsigned u[4]; bf16x8 v; } pa0, pa1;
    if (hi == 0) {
      pa0.u[0] = w[0]; pa0.u[1] = w[1]; pa0.u[2] = s0; pa0.u[3] = s1;
      pa1.u[0] = w[4]; pa1.u[1] = w[5]; pa1.u[2] = s4; pa1.u[3] = s5;
    } else {
      pa0.u[0] = s2; pa0.u[1] = s3; pa0.u[2] = w[2]; pa0.u[3] = w[3];
      pa1.u[0] = s6; pa1.u[1] = s7; pa1.u[2] = w[6]; pa1.u[3] = w[7];
    }
    // ---- PV: V loaded HERE (late, R4-style) from coalesced tiles ----
    const bf16_t* vp = vb + ((size_t)kt << 11) + c * 32 + hi * 8;
    bf16x8 v00 = *reinterpret_cast<const bf16x8*>(vp);
    bf16x8 v01 = *reinterpret_cast<const bf16x8*>(vp + 16);
    bf16x8 v10 = *reinterpret_cast<const bf16x8*>(vp + 1024);
    bf16x8 v11 = *reinterpret_cast<const bf16x8*>(vp + 1024 + 16);
    acc0 = mfma32(pa0.v, v00, acc0);
    acc0 = mfma32(pa1.v, v01, acc0);
    acc1 = mfma32(pa0.v, v10, acc1);
    acc1 = mfma32(pa1.v, v11, acc1);
  }

  // ---- merge the two k-half partials ----
  mls[pair][kh][0][c] = m_run;
  mls[pair][kh][1][c] = l_run;
  __syncthreads();
  const float mo = mls[pair][kh ^ 1][0][c];
  const float lo = mls[pair][kh ^ 1][1][c];
  const float mt = fmaxf(m_run, mo);
  const float sc_self = exp2f(m_run - mt);
#pragma unroll
  for (int r = 0; r < 16; ++r) {
    const int qi = (r & 3) + 8 * (r >> 2) + 4 * hi;
    const float scr = __shfl(sc_self, qi, 64);
    acc0[r] *= scr;
    acc1[r] *= scr;
  }
  if (kh == 1) {
#pragma unroll
    for (int r = 0; r < 16; ++r) {
      accbuf[pair][lane][r] = acc0[r];
      accbuf[pair][lane][r + 16] = acc1[r];
    }
  }
  __syncthreads();
  if (kh == 0) {
    const float l_tot = l_run * sc_self + lo * exp2f(mo - mt);
#pragma unroll
    for (int r = 0; r < 16; ++r) {
      acc0[r] += accbuf[pair][lane][r];
      acc1[r] += accbuf[pair][lane][r + 16];
    }
#pragma unroll
    for (int r = 0; r < 16; ++r) {
      const int qi = (r & 3) + 8 * (r >> 2) + 4 * hi;
      const float lr = __shfl(l_tot, qi, 64);
      const float inv = 1.0f / lr;
      bf16_t* op = ao + ((size_t)(b * S + qbase + qi)) * 1024 + h * 64 + c;
      op[0]  = (bf16_t)(acc0[r] * inv);
      op[32] = (bf16_t)(acc1[r] * inv);
    }
  }
}

extern "C" void kernel_launch(void* const* d_in, const int* in_sizes, int n_in,
                              void* d_out, int out_size, void* d_ws, size_t ws_size,
                              hipStream_t stream) {
  const float* features = (const float*)d_in[0];
  const float* wq = (const float*)d_in[1];
  const float* wk = (const float*)d_in[2];
  const float* wv = (const float*)d_in[3];
  const float* wo = (const float*)d_in[4];
  const float* qw = (const float*)d_in[5];
  const float* kw = (const float*)d_in[6];
  float* out = (float*)d_out;

  bf16_t* Xbf  = (bf16_t*)d_ws;
  bf16_t* Wqkv = Xbf + 4096 * 1024;
  bf16_t* Wo   = Wqkv + 1536 * 1024;
  float*  QKVr = (float*)(Wo + 1024 * 1024);
  bf16_t* Qn   = (bf16_t*)(QKVr + 4096 * 1536);
  bf16_t* Kn   = Qn + 2 * 16 * 2048 * 64;
  bf16_t* Vt   = Kn + 2 * 4 * 2048 * 64;
  bf16_t* Ao   = Vt + 2 * 4 * 64 * 2048;

  cast_all_k<<<6656, 256, 0, stream>>>(features, wq, wk, wv, wo, Xbf, Wqkv, Wo);
  gemm_bt<<<dim3(12, 32), 256, 0, stream>>>(Xbf, Wqkv, QKVr, 4096, 1536, 1024);
  rmsnorm_k<<<4096, 256, 0, stream>>>(QKVr, qw, kw, Qn, Kn);
  transpose_v_k<<<dim3(32, 8), 256, 0, stream>>>(QKVr, Vt);
  attn_k<<<dim3(8, 32, 4), 256, 0, stream>>>(Qn, Kn, Vt, Ao);
  gemm_bt<<<dim3(8, 32), 256, 0, stream>>>(Ao, Wo, out, 4096, 1024, 1024);
}